// Round 3
// baseline (3523.430 us; speedup 1.0000x reference)
//
#include <hip/hip_runtime.h>

#define BB 512
#define TT 2048
#define DD 8
#define HH 64
#define GG 256  // 4*H gates

__device__ __forceinline__ float rlane(float v, int l) {
  return __int_as_float(__builtin_amdgcn_readlane(__float_as_int(v), l));
}
__device__ __forceinline__ float sigm(float x) {
  return 1.0f / (1.0f + __expf(-x));
}
__device__ __forceinline__ float tanh_fast(float x) {
  // tanh(x) = 1 - 2/(exp(2x)+1); saturates correctly at +/-inf
  return 1.0f - 2.0f / (__expf(2.0f * x) + 1.0f);
}

// Residency story (round 0 evidence): VGPR_Count=108 with a ~200-float
// per-thread weight footprint proves the weights were re-streamed from
// L2/scratch every one of the 2048 timesteps (~4600 cyc/step of traffic
// ~= the measured 4070 cyc/step). amdgpu_waves_per_eu(2,2) was IGNORED
// by the allocator (it targeted ~4 waves/EU -> 108 regs -> remat).
//
// Fix: the documented knob. __launch_bounds__(256, 1) = min 1 wave/EU
// -> VGPR budget up to 512. Weight demand ~235 regs leaves ~270 regs of
// slack: no spill possible, remat unprofitable. No asm pinning (rounds
// 1-2 showed the KEEPF approach is a crash surface), no extra attributes.
// Expected VGPR_Count ~230-290; if it comes back ~108 the next move is
// LDS-chunk staging (ds_read results are not rematerializable).
__global__ void __launch_bounds__(256, 1)
    lstm2_fused(
        const float* __restrict__ x,
        const float* __restrict__ w_ih0, const float* __restrict__ w_hh0,
        const float* __restrict__ b_ih0, const float* __restrict__ b_hh0,
        const float* __restrict__ w_ih1, const float* __restrict__ w_hh1,
        const float* __restrict__ b_ih1, const float* __restrict__ b_hh1,
        const float* __restrict__ w_out, const float* __restrict__ b_out,
        float* __restrict__ out)
{
  const int b    = blockIdx.x;
  const int tid  = threadIdx.x;   // gate index g
  const int lane = tid & 63;
  const int wave = tid >> 6;      // 0:i 1:f 2:g 3:o

  __shared__ float g0buf[2][GG];
  __shared__ float g1buf[2][GG];

  // ---- one-time: this thread's weight rows into registers ----
  float wih0[DD];   // w_ih0 row tid (consumes x[t])
  float wa[HH];     // w_ih1 row tid (consumes h0[t])
  float wb[HH];     // w_hh0 row tid (consumes h0[t] -> next-step layer0)
  float wc[HH];     // w_hh1 row tid (consumes h1[t-1])
  {
    const float4* pa = reinterpret_cast<const float4*>(w_ih1 + tid * HH);
    const float4* pb = reinterpret_cast<const float4*>(w_hh0 + tid * HH);
    const float4* pc = reinterpret_cast<const float4*>(w_hh1 + tid * HH);
#pragma unroll
    for (int q = 0; q < HH / 4; ++q) {
      const float4 va = pa[q];
      wa[4 * q + 0] = va.x; wa[4 * q + 1] = va.y;
      wa[4 * q + 2] = va.z; wa[4 * q + 3] = va.w;
    }
#pragma unroll
    for (int q = 0; q < HH / 4; ++q) {
      const float4 vb = pb[q];
      wb[4 * q + 0] = vb.x; wb[4 * q + 1] = vb.y;
      wb[4 * q + 2] = vb.z; wb[4 * q + 3] = vb.w;
    }
#pragma unroll
    for (int q = 0; q < HH / 4; ++q) {
      const float4 vc = pc[q];
      wc[4 * q + 0] = vc.x; wc[4 * q + 1] = vc.y;
      wc[4 * q + 2] = vc.z; wc[4 * q + 3] = vc.w;
    }
#pragma unroll
    for (int q = 0; q < DD / 4; ++q) {
      const float4 vi = reinterpret_cast<const float4*>(w_ih0 + tid * DD)[q];
      wih0[4 * q + 0] = vi.x; wih0[4 * q + 1] = vi.y;
      wih0[4 * q + 2] = vi.z; wih0[4 * q + 3] = vi.w;
    }
  }

  const float bias0 = b_ih0[tid] + b_hh0[tid];
  const float bias1 = b_ih1[tid] + b_hh1[tid];

  // per-wave replicated state: lane j holds element j
  float h0 = 0.0f, c0 = 0.0f, h1 = 0.0f, c1 = 0.0f;
  // layer0 preactivation carried across steps: acc0 = bias0 + Whh0.h0[t-1]
  float acc0 = bias0;

  const float4* xb4 = reinterpret_cast<const float4*>(x + (size_t)b * TT * DD);
  float4 xa = xb4[0], xb_ = xb4[1];  // x[t=0] (wave-uniform)

  for (int t = 0; t < TT; ++t) {
    const int p = t & 1;

    // ---- layer 0: add x contribution ----
    acc0 = fmaf(wih0[0], xa.x, acc0);
    acc0 = fmaf(wih0[1], xa.y, acc0);
    acc0 = fmaf(wih0[2], xa.z, acc0);
    acc0 = fmaf(wih0[3], xa.w, acc0);
    acc0 = fmaf(wih0[4], xb_.x, acc0);
    acc0 = fmaf(wih0[5], xb_.y, acc0);
    acc0 = fmaf(wih0[6], xb_.z, acc0);
    acc0 = fmaf(wih0[7], xb_.w, acc0);

    // prefetch next step's x (consumed a full step later)
    {
      const int tn = (t + 1 < TT) ? (t + 1) : (TT - 1);
      xa  = xb4[2 * tn];
      xb_ = xb4[2 * tn + 1];
    }

    const float a0 = (wave == 2) ? tanh_fast(acc0) : sigm(acc0);
    g0buf[p][tid] = a0;
    __syncthreads();
    {
      const float gi = g0buf[p][lane];
      const float gf = g0buf[p][HH + lane];
      const float gg = g0buf[p][2 * HH + lane];
      const float go = g0buf[p][3 * HH + lane];
      c0 = fmaf(gf, c0, gi * gg);
      h0 = go * tanh_fast(c0);
    }

    // ---- fused: layer1 gates (wa.h0 + wc.h1prev) + next-step layer0 (wb.h0)
    // even/odd partial accumulators: 32-deep chains instead of 64-deep
    float s1a = 0.0f,  s1b = 0.0f;   // wa . h0
    float s0a = bias0, s0b = 0.0f;   // wb . h0   (next-step acc0)
    float sca = 0.0f,  scb = 0.0f;   // wc . h1[t-1]
#pragma unroll
    for (int k = 0; k < HH; k += 2) {
      const float h0e = rlane(h0, k);
      const float h0o = rlane(h0, k + 1);
      const float h1e = rlane(h1, k);
      const float h1o = rlane(h1, k + 1);
      s1a = fmaf(wa[k],     h0e, s1a);
      s1b = fmaf(wa[k + 1], h0o, s1b);
      s0a = fmaf(wb[k],     h0e, s0a);
      s0b = fmaf(wb[k + 1], h0o, s0b);
      sca = fmaf(wc[k],     h1e, sca);
      scb = fmaf(wc[k + 1], h1o, scb);
    }
    const float accg1 = bias1 + (s1a + s1b) + (sca + scb);

    const float a1 = (wave == 2) ? tanh_fast(accg1) : sigm(accg1);
    g1buf[p][tid] = a1;
    __syncthreads();
    {
      const float gi = g1buf[p][lane];
      const float gf = g1buf[p][HH + lane];
      const float gg = g1buf[p][2 * HH + lane];
      const float go = g1buf[p][3 * HH + lane];
      c1 = fmaf(gf, c1, gi * gg);
      h1 = go * tanh_fast(c1);
    }
    acc0 = s0a + s0b;
  }

  // ---- head: out[b] = dot(h1, w_out) + b_out ----
  float v = h1 * w_out[lane];
#pragma unroll
  for (int off = 32; off; off >>= 1) v += __shfl_down(v, off);
  if (tid == 0) out[b] = v + b_out[0];
}

extern "C" void kernel_launch(void* const* d_in, const int* in_sizes, int n_in,
                              void* d_out, int out_size, void* d_ws, size_t ws_size,
                              hipStream_t stream) {
  const float* x     = (const float*)d_in[0];
  const float* w_ih0 = (const float*)d_in[1];
  const float* w_hh0 = (const float*)d_in[2];
  const float* b_ih0 = (const float*)d_in[3];
  const float* b_hh0 = (const float*)d_in[4];
  const float* w_ih1 = (const float*)d_in[5];
  const float* w_hh1 = (const float*)d_in[6];
  const float* b_ih1 = (const float*)d_in[7];
  const float* b_hh1 = (const float*)d_in[8];
  const float* w_out = (const float*)d_in[9];
  const float* b_out = (const float*)d_in[10];
  float* out = (float*)d_out;

  lstm2_fused<<<dim3(BB), dim3(256), 0, stream>>>(
      x, w_ih0, w_hh0, b_ih0, b_hh0,
      w_ih1, w_hh1, b_ih1, b_hh1,
      w_out, b_out, out);
}

// Round 4
// 3500.180 us; speedup vs baseline: 1.0066x; 1.0066x over previous
//
#include <hip/hip_runtime.h>

#define BB 512
#define TT 2048
#define DD 8
#define HH 64
#define GG 256  // 4*H gates

typedef float f32x4 __attribute__((ext_vector_type(4)));

__device__ __forceinline__ float rlane(float v, int l) {
  return __int_as_float(__builtin_amdgcn_readlane(__float_as_int(v), l));
}
__device__ __forceinline__ float sigm(float x) {
  return 1.0f / (1.0f + __expf(-x));
}
__device__ __forceinline__ float tanh_fast(float x) {
  // tanh(x) = 1 - 2/(exp(2x)+1); saturates correctly at +/-inf
  return 1.0f - 2.0f / (__expf(2.0f * x) + 1.0f);
}

// Residency evidence trail:
//  R0: waves_per_eu(2,2)            -> VGPR=108, 3466us (remat: weights
//      re-streamed from L2 every one of 2048 steps; ~4600 cyc/step traffic
//      matches measured 4070 cyc/step).
//  R3: __launch_bounds__(256,1)     -> VGPR STILL 108, 3523us. The allocator
//      is not capped -- it PREFERS remat (loop has zero global stores, so
//      weight loads are trivially rematerializable). No occupancy knob can
//      change that; only non-rematerializable values (asm-defined) force
//      residency.
//  R1: asm pin + HARD 256-reg cap   -> runtime abort (RA at the cap).
//  R2: asm pin, no cap              -> never ran (container infra failure).
// This round: pin as 48 float4 TUPLES via 16 asm statements (minimal RA
// constraint surface), NO hard cap anywhere. waves_per_eu(1,2) lets the
// scheduler settle at ~240 regs / 2 waves per EU instead of targeting 4.
#define KEEP3(a, b, c) asm volatile("" : "+v"(a), "+v"(b), "+v"(c))

__global__ void __launch_bounds__(256)
    __attribute__((amdgpu_waves_per_eu(1, 2)))
    lstm2_fused(
        const float* __restrict__ x,
        const float* __restrict__ w_ih0, const float* __restrict__ w_hh0,
        const float* __restrict__ b_ih0, const float* __restrict__ b_hh0,
        const float* __restrict__ w_ih1, const float* __restrict__ w_hh1,
        const float* __restrict__ b_ih1, const float* __restrict__ b_hh1,
        const float* __restrict__ w_out, const float* __restrict__ b_out,
        float* __restrict__ out)
{
  const int b    = blockIdx.x;
  const int tid  = threadIdx.x;   // gate index g
  const int lane = tid & 63;
  const int wave = tid >> 6;      // 0:i 1:f 2:g 3:o

  __shared__ float g0buf[2][GG];
  __shared__ float g1buf[2][GG];

  // ---- one-time: this thread's weight rows into register tuples ----
  float wih0[DD];    // w_ih0 row (NOT pinned; remat = 2 cheap loads/step)
  f32x4 wa4[16];     // w_ih1 row tid  (consumes h0[t])
  f32x4 wb4[16];     // w_hh0 row tid  (consumes h0[t] -> next-step layer0)
  f32x4 wc4[16];     // w_hh1 row tid  (consumes h1[t-1])
  {
    const f32x4* pa = reinterpret_cast<const f32x4*>(w_ih1 + tid * HH);
    const f32x4* pb = reinterpret_cast<const f32x4*>(w_hh0 + tid * HH);
    const f32x4* pc = reinterpret_cast<const f32x4*>(w_hh1 + tid * HH);
#pragma unroll
    for (int q = 0; q < 16; ++q) wa4[q] = pa[q];
#pragma unroll
    for (int q = 0; q < 16; ++q) wb4[q] = pb[q];
#pragma unroll
    for (int q = 0; q < 16; ++q) wc4[q] = pc[q];
#pragma unroll
    for (int k = 0; k < DD; ++k) wih0[k] = w_ih0[tid * DD + k];
  }
  // force residency: 48 quad-tuples (192 VGPRs) become non-rematerializable
#pragma unroll
  for (int q = 0; q < 16; ++q) { KEEP3(wa4[q], wb4[q], wc4[q]); }

  const float bias0 = b_ih0[tid] + b_hh0[tid];
  const float bias1 = b_ih1[tid] + b_hh1[tid];

  // per-wave replicated state: lane j holds element j
  float h0 = 0.0f, c0 = 0.0f, h1 = 0.0f, c1 = 0.0f;
  // layer0 preactivation carried across steps: acc0 = bias0 + Whh0.h0[t-1]
  float acc0 = bias0;

  const float4* xb4 = reinterpret_cast<const float4*>(x + (size_t)b * TT * DD);
  float4 xa = xb4[0], xb_ = xb4[1];  // x[t=0] (wave-uniform)

  for (int t = 0; t < TT; ++t) {
    const int p = t & 1;

    // ---- layer 0: add x contribution ----
    acc0 = fmaf(wih0[0], xa.x, acc0);
    acc0 = fmaf(wih0[1], xa.y, acc0);
    acc0 = fmaf(wih0[2], xa.z, acc0);
    acc0 = fmaf(wih0[3], xa.w, acc0);
    acc0 = fmaf(wih0[4], xb_.x, acc0);
    acc0 = fmaf(wih0[5], xb_.y, acc0);
    acc0 = fmaf(wih0[6], xb_.z, acc0);
    acc0 = fmaf(wih0[7], xb_.w, acc0);

    // prefetch next step's x (consumed a full step later)
    {
      const int tn = (t + 1 < TT) ? (t + 1) : (TT - 1);
      xa  = xb4[2 * tn];
      xb_ = xb4[2 * tn + 1];
    }

    const float a0 = (wave == 2) ? tanh_fast(acc0) : sigm(acc0);
    g0buf[p][tid] = a0;
    __syncthreads();
    {
      const float gi = g0buf[p][lane];
      const float gf = g0buf[p][HH + lane];
      const float gg = g0buf[p][2 * HH + lane];
      const float go = g0buf[p][3 * HH + lane];
      c0 = fmaf(gf, c0, gi * gg);
      h0 = go * tanh_fast(c0);
    }

    // ---- fused: layer1 gates (wa.h0 + wc.h1prev) + next-step layer0 (wb.h0)
    // even/odd partial accumulators: 32-deep chains instead of 64-deep
    float s1a = 0.0f,  s1b = 0.0f;   // wa . h0
    float s0a = bias0, s0b = 0.0f;   // wb . h0   (next-step acc0)
    float sca = bias1, scb = 0.0f;   // wc . h1[t-1]
#pragma unroll
    for (int q = 0; q < 16; ++q) {
#pragma unroll
      for (int j = 0; j < 4; j += 2) {
        const int k = 4 * q + j;
        const float h0e = rlane(h0, k);
        const float h0o = rlane(h0, k + 1);
        const float h1e = rlane(h1, k);
        const float h1o = rlane(h1, k + 1);
        s1a = fmaf(wa4[q][j],     h0e, s1a);
        s1b = fmaf(wa4[q][j + 1], h0o, s1b);
        s0a = fmaf(wb4[q][j],     h0e, s0a);
        s0b = fmaf(wb4[q][j + 1], h0o, s0b);
        sca = fmaf(wc4[q][j],     h1e, sca);
        scb = fmaf(wc4[q][j + 1], h1o, scb);
      }
    }
    const float accg1 = (s1a + s1b) + (sca + scb);

    const float a1 = (wave == 2) ? tanh_fast(accg1) : sigm(accg1);
    g1buf[p][tid] = a1;
    __syncthreads();
    {
      const float gi = g1buf[p][lane];
      const float gf = g1buf[p][HH + lane];
      const float gg = g1buf[p][2 * HH + lane];
      const float go = g1buf[p][3 * HH + lane];
      c1 = fmaf(gf, c1, gi * gg);
      h1 = go * tanh_fast(c1);
    }
    acc0 = s0a + s0b;
  }

  // ---- head: out[b] = dot(h1, w_out) + b_out ----
  float v = h1 * w_out[lane];
#pragma unroll
  for (int off = 32; off; off >>= 1) v += __shfl_down(v, off);
  if (tid == 0) out[b] = v + b_out[0];
}

extern "C" void kernel_launch(void* const* d_in, const int* in_sizes, int n_in,
                              void* d_out, int out_size, void* d_ws, size_t ws_size,
                              hipStream_t stream) {
  const float* x     = (const float*)d_in[0];
  const float* w_ih0 = (const float*)d_in[1];
  const float* w_hh0 = (const float*)d_in[2];
  const float* b_ih0 = (const float*)d_in[3];
  const float* b_hh0 = (const float*)d_in[4];
  const float* w_ih1 = (const float*)d_in[5];
  const float* w_hh1 = (const float*)d_in[6];
  const float* b_ih1 = (const float*)d_in[7];
  const float* b_hh1 = (const float*)d_in[8];
  const float* w_out = (const float*)d_in[9];
  const float* b_out = (const float*)d_in[10];
  float* out = (float*)d_out;

  lstm2_fused<<<dim3(BB), dim3(256), 0, stream>>>(
      x, w_ih0, w_hh0, b_ih0, b_hh0,
      w_ih1, w_hh1, b_ih1, b_hh1,
      w_out, b_out, out);
}